// Round 3
// baseline (717.492 us; speedup 1.0000x reference)
//
#include <hip/hip_runtime.h>
#include <stdint.h>

typedef __attribute__((ext_vector_type(8))) short short8;
typedef __attribute__((ext_vector_type(16))) float f32x16;

#define LOG2E 1.4426950408889634f

__device__ inline float fast_exp2(float x) {
#if __has_builtin(__builtin_amdgcn_exp2f)
  return __builtin_amdgcn_exp2f(x);
#else
  float r;
  asm volatile("v_exp_f32 %0, %1" : "=v"(r) : "v"(x));
  return r;
#endif
}

// XOR-swizzle: spread 16B granules of a [64][256B] row-major tile across bank
// clusters. Row = byte_off>>8; XOR bits 4..6 with (row&7). Involution.
__device__ inline unsigned swz(unsigned off) {
  return off ^ (((off >> 8) & 7u) << 4);
}

// Split 8 f32 (optionally scaled) into bf16 hi + bf16 lo (truncation split;
// |x - hi - lo| <= 2^-16 |x|).
__device__ inline void split8(float x0, float x1, float x2, float x3,
                              float x4, float x5, float x6, float x7,
                              float scale, short8& hi, short8& lo) {
  float xs[8] = {x0, x1, x2, x3, x4, x5, x6, x7};
#pragma unroll
  for (int i = 0; i < 8; ++i) {
    float v = xs[i] * scale;
    unsigned u = __float_as_uint(v);
    float hf = __uint_as_float(u & 0xffff0000u);
    float rr = v - hf;  // exact
    hi[i] = (short)(u >> 16);
    lo[i] = (short)(__float_as_uint(rr) >> 16);
  }
}

// ---------------------------------------------------------------------------
// Preprocess: s[m] = exp(-||y_m||^2/2) * w[m];  pref[n] = exp(-||x_n||^2/2)
// One 64-lane wave per row (4 rows per 256-thread block).
// ---------------------------------------------------------------------------
__global__ __launch_bounds__(256) void gk_prep(
    const float* __restrict__ Xnew, const float* __restrict__ Xtr,
    const float* __restrict__ w, float* __restrict__ s,
    float* __restrict__ pref, int M, int N) {
  int row = blockIdx.x * 4 + (threadIdx.x >> 6);
  int lane = threadIdx.x & 63;
  if (row >= M + N) return;
  const float* src =
      (row < M) ? (Xtr + (size_t)row * 128) : (Xnew + (size_t)(row - M) * 128);
  float2 v = *(const float2*)(src + lane * 2);
  float ss = v.x * v.x + v.y * v.y;
#pragma unroll
  for (int o = 32; o >= 1; o >>= 1) ss += __shfl_xor(ss, o, 64);
  if (lane == 0) {
    float e = expf(-0.5f * ss);
    if (row < M)
      s[row] = e * w[row];
    else
      pref[row - M] = e;
  }
}

// ---------------------------------------------------------------------------
// Main kernel: block = 4 waves, 256 output cols (X_new panel, in registers as
// bf16 hi/lo scaled by log2e), streaming 64 X_train rows/iter through LDS.
// R1 structure (2-barrier, single 33 KB buffer) at 4 blocks/CU: grid = 1024
// blocks exactly fills 256 CUs x4; independent blocks on a CU cover each
// other's barrier drains. LDS 33280 B x4 = 133 KB/CU; VGPR capped at 128 by
// __launch_bounds__(256,4) -> 16 waves/CU.
// acc = log2e * <x_n, y_m>;  out_n += sum_m exp2(acc) * s[m]; atomic at end.
// ---------------------------------------------------------------------------
__global__ __launch_bounds__(256, 4) void gk_main(
    const float* __restrict__ Xnew, const float* __restrict__ Xtr,
    const float* __restrict__ s, const float* __restrict__ pref,
    float* __restrict__ out, int N, int M, int mchunk) {
  __shared__ __attribute__((aligned(16))) char lds[33024];
  // layout: Ah [0,16384), Al [16384,32768), s-chunk [32768, 33024)

  const int t = threadIdx.x;
  const int l = t & 63;
  const int w = t >> 6;
  const int lrow = l & 31;  // A row / B col within 32-frag
  const int lk = l >> 5;    // k half

  const int n0 = blockIdx.x * 256;
  const int M0 = blockIdx.y * mchunk;
  const int iters = mchunk >> 6;

  // ---- load B (X_new panel) once into registers, scaled by LOG2E ----------
  short8 bh[2][8], bl[2][8];
  {
    const int colbase = n0 + w * 64;
#pragma unroll
    for (int nf = 0; nf < 2; ++nf) {
      int col = colbase + nf * 32 + lrow;
      const float* p = Xnew + (size_t)col * 128 + lk * 8;
#pragma unroll
      for (int kf = 0; kf < 8; ++kf) {
        float4 f0 = *(const float4*)(p + kf * 16);
        float4 f1 = *(const float4*)(p + kf * 16 + 4);
        split8(f0.x, f0.y, f0.z, f0.w, f1.x, f1.y, f1.z, f1.w, LOG2E,
               bh[nf][kf], bl[nf][kf]);
      }
    }
  }

  float out0 = 0.f, out1 = 0.f;

  // staging registers (f32 A tile chunk: 4 chunks x 8 floats)
  float4 ga[4][2];
  float sreg = 0.f;

  // prologue: issue global loads for iter 0
  {
    const float* abase = Xtr + (size_t)M0 * 128;
#pragma unroll
    for (int j = 0; j < 4; ++j) {
      int c = t + j * 256;
      int row = c >> 4, oct = c & 15;
      const float* p = abase + (size_t)row * 128 + oct * 8;
      ga[j][0] = *(const float4*)p;
      ga[j][1] = *(const float4*)(p + 4);
    }
    if (t < 64) sreg = s[M0 + t];
  }

#pragma unroll 1
  for (int it = 0; it < iters; ++it) {
    __syncthreads();  // all waves done reading LDS from previous iter

    // ---- convert staged f32 -> bf16 hi/lo, write swizzled to LDS ----------
#pragma unroll
    for (int j = 0; j < 4; ++j) {
      int c = t + j * 256;
      int row = c >> 4, oct = c & 15;
      unsigned off = swz((unsigned)(row * 256 + oct * 16));
      short8 hi, lo;
      split8(ga[j][0].x, ga[j][0].y, ga[j][0].z, ga[j][0].w, ga[j][1].x,
             ga[j][1].y, ga[j][1].z, ga[j][1].w, 1.0f, hi, lo);
      *(short8*)(lds + off) = hi;
      *(short8*)(lds + 16384 + off) = lo;
    }
    if (t < 64) *(float*)(lds + 32768 + t * 4) = sreg;

    // ---- issue next-iter global loads (in flight across compute) ----------
    if (it + 1 < iters) {
      const float* abase = Xtr + (size_t)(M0 + (it + 1) * 64) * 128;
#pragma unroll
      for (int j = 0; j < 4; ++j) {
        int c = t + j * 256;
        int row = c >> 4, oct = c & 15;
        const float* p = abase + (size_t)row * 128 + oct * 8;
        ga[j][0] = *(const float4*)p;
        ga[j][1] = *(const float4*)(p + 4);
      }
      if (t < 64) sreg = s[M0 + (it + 1) * 64 + t];
    }

    __syncthreads();  // LDS tile ready

    // ---- compute: 2 m-frags x 2 n-frags of 32x32, K=128, bf16x3 ----------
#pragma unroll
    for (int mf = 0; mf < 2; ++mf) {
      f32x16 acc0 = {0, 0, 0, 0, 0, 0, 0, 0, 0, 0, 0, 0, 0, 0, 0, 0};
      f32x16 acc1 = {0, 0, 0, 0, 0, 0, 0, 0, 0, 0, 0, 0, 0, 0, 0, 0};
#pragma unroll
      for (int kf = 0; kf < 8; ++kf) {
        unsigned off =
            swz((unsigned)((mf * 32 + lrow) * 256 + kf * 32 + lk * 16));
        short8 ah = *(const short8*)(lds + off);
        short8 al = *(const short8*)(lds + 16384 + off);
        acc0 = __builtin_amdgcn_mfma_f32_32x32x16_bf16(ah, bh[0][kf], acc0, 0, 0, 0);
        acc1 = __builtin_amdgcn_mfma_f32_32x32x16_bf16(ah, bh[1][kf], acc1, 0, 0, 0);
        acc0 = __builtin_amdgcn_mfma_f32_32x32x16_bf16(ah, bl[0][kf], acc0, 0, 0, 0);
        acc1 = __builtin_amdgcn_mfma_f32_32x32x16_bf16(ah, bl[1][kf], acc1, 0, 0, 0);
        acc0 = __builtin_amdgcn_mfma_f32_32x32x16_bf16(al, bh[0][kf], acc0, 0, 0, 0);
        acc1 = __builtin_amdgcn_mfma_f32_32x32x16_bf16(al, bh[1][kf], acc1, 0, 0, 0);
      }
      // epilogue: exp2 + weighted row-sum. C/D layout (verified):
      // col = lane&31, row = (reg&3) + 8*(reg>>2) + 4*(lane>>5)
      const float* sl = (const float*)(lds + 32768 + mf * 128);
#pragma unroll
      for (int r = 0; r < 16; ++r) {
        int row = (r & 3) + 8 * (r >> 2) + 4 * lk;
        float sv = sl[row];
        out0 += fast_exp2(acc0[r]) * sv;
        out1 += fast_exp2(acc1[r]) * sv;
      }
    }
  }

  // ---- cross-lane m-reduction (rows split across lane>>5) + atomic --------
  out0 += __shfl_xor(out0, 32, 64);
  out1 += __shfl_xor(out1, 32, 64);
  if (l < 32) {
    int n = n0 + w * 64 + l;
    atomicAdd(out + n, pref[n] * out0);
    n += 32;
    atomicAdd(out + n, pref[n] * out1);
  }
}

extern "C" void kernel_launch(void* const* d_in, const int* in_sizes, int n_in,
                              void* d_out, int out_size, void* d_ws,
                              size_t ws_size, hipStream_t stream) {
  const float* Xnew = (const float*)d_in[0];
  const float* Xtr = (const float*)d_in[1];
  const float* wts = (const float*)d_in[2];
  float* out = (float*)d_out;

  const int N = in_sizes[0] / 128;  // 8192
  const int M = in_sizes[1] / 128;  // 32768

  float* s_ws = (float*)d_ws;        // [M]
  float* pref_ws = s_ws + M;         // [N]

  hipMemsetAsync(d_out, 0, (size_t)N * sizeof(float), stream);

  int rows = M + N;
  gk_prep<<<dim3((rows + 3) / 4), 256, 0, stream>>>(Xnew, Xtr, wts, s_ws,
                                                    pref_ws, M, N);

  const int SPLIT = 32;  // grid = 32 x 32 = 1024 blocks = exactly 4 per CU
  dim3 grid(N / 256, SPLIT);
  gk_main<<<grid, 256, 0, stream>>>(Xnew, Xtr, s_ws, pref_ws, out, N, M,
                                    M / SPLIT);
}

// Round 4
// 182.740 us; speedup vs baseline: 3.9263x; 3.9263x over previous
//
#include <hip/hip_runtime.h>
#include <stdint.h>

typedef __attribute__((ext_vector_type(8))) short short8;
typedef __attribute__((ext_vector_type(16))) float f32x16;

#define LOG2E 1.4426950408889634f

__device__ inline float fast_exp2(float x) {
#if __has_builtin(__builtin_amdgcn_exp2f)
  return __builtin_amdgcn_exp2f(x);
#else
  float r;
  asm volatile("v_exp_f32 %0, %1" : "=v"(r) : "v"(x));
  return r;
#endif
}

// XOR-swizzle: spread 16B granules of a [64][256B] row-major tile across bank
// clusters. Row = byte_off>>8; XOR bits 4..6 with (row&7). Involution.
__device__ inline unsigned swz(unsigned off) {
  return off ^ (((off >> 8) & 7u) << 4);
}

__device__ inline void gload16(const void* g, void* l) {
  __builtin_amdgcn_global_load_lds(
      (const __attribute__((address_space(1))) void*)g,
      (__attribute__((address_space(3))) void*)l, 16, 0, 0);
}
__device__ inline void gload4(const void* g, void* l) {
  __builtin_amdgcn_global_load_lds(
      (const __attribute__((address_space(1))) void*)g,
      (__attribute__((address_space(3))) void*)l, 4, 0, 0);
}

// Split 8 f32 (optionally scaled) into bf16 hi + bf16 lo (truncation split;
// |x - hi - lo| <= 2^-16 |x|).
__device__ inline void split8(float x0, float x1, float x2, float x3,
                              float x4, float x5, float x6, float x7,
                              float scale, short8& hi, short8& lo) {
  float xs[8] = {x0, x1, x2, x3, x4, x5, x6, x7};
#pragma unroll
  for (int i = 0; i < 8; ++i) {
    float v = xs[i] * scale;
    unsigned u = __float_as_uint(v);
    float hf = __uint_as_float(u & 0xffff0000u);
    float rr = v - hf;  // exact
    hi[i] = (short)(u >> 16);
    lo[i] = (short)(__float_as_uint(rr) >> 16);
  }
}

// ---------------------------------------------------------------------------
// Preprocess: s[m] = exp(-||y_m||^2/2) * w[m];  pref[n] = exp(-||x_n||^2/2)
// ---------------------------------------------------------------------------
__global__ __launch_bounds__(256) void gk_prep(
    const float* __restrict__ Xnew, const float* __restrict__ Xtr,
    const float* __restrict__ w, float* __restrict__ s,
    float* __restrict__ pref, int M, int N) {
  int row = blockIdx.x * 4 + (threadIdx.x >> 6);
  int lane = threadIdx.x & 63;
  if (row >= M + N) return;
  const float* src =
      (row < M) ? (Xtr + (size_t)row * 128) : (Xnew + (size_t)(row - M) * 128);
  float2 v = *(const float2*)(src + lane * 2);
  float ss = v.x * v.x + v.y * v.y;
#pragma unroll
  for (int o = 32; o >= 1; o >>= 1) ss += __shfl_xor(ss, o, 64);
  if (lane == 0) {
    float e = expf(-0.5f * ss);
    if (row < M)
      s[row] = e * w[row];
    else
      pref[row - M] = e;
  }
}

// ---------------------------------------------------------------------------
// One-time conversion: Xtr f32 -> bf16 hi/lo planes, stored PRE-SWIZZLED per
// 64-row tile (16 KB per tile per plane) so the main kernel can
// global_load_lds LINEARLY and read with swz() (rule: inverse-swz source +
// swz read = consistent).  One thread per 16B granule.
// ---------------------------------------------------------------------------
__global__ __launch_bounds__(256) void gk_conv(const float* __restrict__ Xtr,
                                               char* __restrict__ hi_out,
                                               char* __restrict__ lo_out,
                                               int M) {
  int g = blockIdx.x * 256 + threadIdx.x;  // global granule id
  int row = g >> 4;
  int gr = g & 15;
  if (row >= M) return;
  const float* p = Xtr + (size_t)row * 128 + gr * 8;
  float4 a = *(const float4*)p;
  float4 b = *(const float4*)(p + 4);
  short8 hi, lo;
  split8(a.x, a.y, a.z, a.w, b.x, b.y, b.z, b.w, 1.0f, hi, lo);
  int tile = row >> 6, r = row & 63;
  unsigned off = swz((unsigned)(r * 256 + gr * 16));
  *(short8*)(hi_out + (size_t)tile * 16384 + off) = hi;
  *(short8*)(lo_out + (size_t)tile * 16384 + off) = lo;
}

// ---------------------------------------------------------------------------
// FAST main kernel: 4 waves, 256 output cols (X_new panel in registers as
// bf16 hi/lo scaled by log2e). X_train tiles (64 rows) stream through
// DOUBLE-BUFFERED dynamic LDS via global_load_lds width-16 from the
// pre-converted planes. T3-minimum 2-phase: stage(buf^1) issued at top of
// compute phase, single __syncthreads at end (its vmcnt(0) drain is covered
// by the MFMA phase). T5 setprio around MFMA clusters.
// LDS: [buf0 hi 16K | buf0 lo 16K | buf1 hi 16K | buf1 lo 16K | s0 256 | s1 256]
// ---------------------------------------------------------------------------
__global__ __launch_bounds__(256, 2) void gk_main_fast(
    const float* __restrict__ Xnew, const char* __restrict__ hi_g,
    const char* __restrict__ lo_g, const float* __restrict__ s,
    const float* __restrict__ pref, float* __restrict__ out, int N, int M,
    int mchunk) {
  extern __shared__ char dlds[];

  const int t = threadIdx.x;
  const int l = t & 63;
  const int w = t >> 6;
  const int lrow = l & 31;
  const int lk = l >> 5;

  const int n0 = blockIdx.x * 256;
  const int M0 = blockIdx.y * mchunk;
  const int tile0 = M0 >> 6;
  const int iters = mchunk >> 6;

  // ---- stage tile 0 into buf 0 (async) ------------------------------------
  {
    const char* srcH = hi_g + (size_t)tile0 * 16384 + w * 4096 + l * 16;
    const char* srcL = lo_g + (size_t)tile0 * 16384 + w * 4096 + l * 16;
    char* dstH = dlds + w * 4096;
    char* dstL = dstH + 16384;
#pragma unroll
    for (int i = 0; i < 4; ++i) {
      gload16(srcH + i * 1024, dstH + i * 1024);
      gload16(srcL + i * 1024, dstL + i * 1024);
    }
    if (w == 0) gload4(s + M0 + l, dlds + 65536);
  }

  // ---- load B (X_new panel) once into registers, scaled by LOG2E ----------
  short8 bh[2][8], bl[2][8];
  {
    const int colbase = n0 + w * 64;
#pragma unroll
    for (int nf = 0; nf < 2; ++nf) {
      int col = colbase + nf * 32 + lrow;
      const float* p = Xnew + (size_t)col * 128 + lk * 8;
#pragma unroll
      for (int kf = 0; kf < 8; ++kf) {
        float4 f0 = *(const float4*)(p + kf * 16);
        float4 f1 = *(const float4*)(p + kf * 16 + 4);
        split8(f0.x, f0.y, f0.z, f0.w, f1.x, f1.y, f1.z, f1.w, LOG2E,
               bh[nf][kf], bl[nf][kf]);
      }
    }
  }

  const unsigned rd_xor = ((unsigned)lrow & 7u) << 4;
  float out0 = 0.f, out1 = 0.f;

  __syncthreads();  // tile 0 landed (vmcnt drain) + visible

#pragma unroll 1
  for (int it = 0; it < iters; ++it) {
    const int cur = it & 1;

    // ---- issue async stage of next tile into other buffer ----------------
    if (it + 1 < iters) {
      const char* srcH =
          hi_g + (size_t)(tile0 + it + 1) * 16384 + w * 4096 + l * 16;
      const char* srcL =
          lo_g + (size_t)(tile0 + it + 1) * 16384 + w * 4096 + l * 16;
      char* dstH = dlds + (cur ^ 1) * 32768 + w * 4096;
      char* dstL = dstH + 16384;
#pragma unroll
      for (int i = 0; i < 4; ++i) {
        gload16(srcH + i * 1024, dstH + i * 1024);
        gload16(srcL + i * 1024, dstL + i * 1024);
      }
      if (w == 0)
        gload4(s + M0 + (it + 1) * 64 + l, dlds + 65536 + (cur ^ 1) * 256);
    }

    // ---- compute current tile: 2 mf x 2 nf of 32x32, K=128, bf16x3 --------
    const char* hiB = dlds + cur * 32768;
    const char* loB = hiB + 16384;
    const char* sB = dlds + 65536 + cur * 256;
#pragma unroll
    for (int mf = 0; mf < 2; ++mf) {
      f32x16 acc0 = {0, 0, 0, 0, 0, 0, 0, 0, 0, 0, 0, 0, 0, 0, 0, 0};
      f32x16 acc1 = {0, 0, 0, 0, 0, 0, 0, 0, 0, 0, 0, 0, 0, 0, 0, 0};
      __builtin_amdgcn_s_setprio(1);
#pragma unroll
      for (int kf = 0; kf < 8; ++kf) {
        unsigned off = ((unsigned)(mf * 32 + lrow) << 8) +
                       (((unsigned)(kf * 32 + lk * 16)) ^ rd_xor);
        short8 ah = *(const short8*)(hiB + off);
        short8 al = *(const short8*)(loB + off);
        acc0 = __builtin_amdgcn_mfma_f32_32x32x16_bf16(ah, bh[0][kf], acc0, 0, 0, 0);
        acc1 = __builtin_amdgcn_mfma_f32_32x32x16_bf16(ah, bh[1][kf], acc1, 0, 0, 0);
        acc0 = __builtin_amdgcn_mfma_f32_32x32x16_bf16(ah, bl[0][kf], acc0, 0, 0, 0);
        acc1 = __builtin_amdgcn_mfma_f32_32x32x16_bf16(ah, bl[1][kf], acc1, 0, 0, 0);
        acc0 = __builtin_amdgcn_mfma_f32_32x32x16_bf16(al, bh[0][kf], acc0, 0, 0, 0);
        acc1 = __builtin_amdgcn_mfma_f32_32x32x16_bf16(al, bh[1][kf], acc1, 0, 0, 0);
      }
      __builtin_amdgcn_s_setprio(0);
      // epilogue: exp2 + weighted row-sum. C/D layout (verified):
      // col = lane&31, row = (reg&3) + 8*(reg>>2) + 4*(lane>>5)
      // rows for reg group q (=r>>2): 8q + 4lk + (r&3)  -> one float4 read.
      const float4* sl4 = (const float4*)(sB + mf * 128);
#pragma unroll
      for (int q = 0; q < 4; ++q) {
        float4 sv = sl4[q * 2 + lk];
#pragma unroll
        for (int j = 0; j < 4; ++j) {
          int r = q * 4 + j;
          float svj = (&sv.x)[j];
          out0 += fast_exp2(acc0[r]) * svj;
          out1 += fast_exp2(acc1[r]) * svj;
        }
      }
    }

    __syncthreads();  // drains staged loads (covered by compute above) +
                      // publishes buf cur^1; protects WAR on next overwrite
  }

  out0 += __shfl_xor(out0, 32, 64);
  out1 += __shfl_xor(out1, 32, 64);
  if (l < 32) {
    int n = n0 + w * 64 + l;
    atomicAdd(out + n, pref[n] * out0);
    n += 32;
    atomicAdd(out + n, pref[n] * out1);
  }
}

// ---------------------------------------------------------------------------
// FALLBACK (ws too small): R1 structure with one fix — next-iter global loads
// are issued AFTER the second barrier, so their vmcnt(0) drain happens at the
// NEXT iteration's first barrier, one full compute phase later.
// ---------------------------------------------------------------------------
__global__ __launch_bounds__(256, 2) void gk_main_fb(
    const float* __restrict__ Xnew, const float* __restrict__ Xtr,
    const float* __restrict__ s, const float* __restrict__ pref,
    float* __restrict__ out, int N, int M, int mchunk) {
  __shared__ __attribute__((aligned(16))) char lds[33024];

  const int t = threadIdx.x;
  const int l = t & 63;
  const int w = t >> 6;
  const int lrow = l & 31;
  const int lk = l >> 5;

  const int n0 = blockIdx.x * 256;
  const int M0 = blockIdx.y * mchunk;
  const int iters = mchunk >> 6;

  short8 bh[2][8], bl[2][8];
  {
    const int colbase = n0 + w * 64;
#pragma unroll
    for (int nf = 0; nf < 2; ++nf) {
      int col = colbase + nf * 32 + lrow;
      const float* p = Xnew + (size_t)col * 128 + lk * 8;
#pragma unroll
      for (int kf = 0; kf < 8; ++kf) {
        float4 f0 = *(const float4*)(p + kf * 16);
        float4 f1 = *(const float4*)(p + kf * 16 + 4);
        split8(f0.x, f0.y, f0.z, f0.w, f1.x, f1.y, f1.z, f1.w, LOG2E,
               bh[nf][kf], bl[nf][kf]);
      }
    }
  }

  float out0 = 0.f, out1 = 0.f;
  float4 ga[4][2];
  float sreg = 0.f;

  {
    const float* abase = Xtr + (size_t)M0 * 128;
#pragma unroll
    for (int j = 0; j < 4; ++j) {
      int c = t + j * 256;
      int row = c >> 4, oct = c & 15;
      const float* p = abase + (size_t)row * 128 + oct * 8;
      ga[j][0] = *(const float4*)p;
      ga[j][1] = *(const float4*)(p + 4);
    }
    if (t < 64) sreg = s[M0 + t];
  }

#pragma unroll 1
  for (int it = 0; it < iters; ++it) {
    __syncthreads();

#pragma unroll
    for (int j = 0; j < 4; ++j) {
      int c = t + j * 256;
      int row = c >> 4, oct = c & 15;
      unsigned off = swz((unsigned)(row * 256 + oct * 16));
      short8 hi, lo;
      split8(ga[j][0].x, ga[j][0].y, ga[j][0].z, ga[j][0].w, ga[j][1].x,
             ga[j][1].y, ga[j][1].z, ga[j][1].w, 1.0f, hi, lo);
      *(short8*)(lds + off) = hi;
      *(short8*)(lds + 16384 + off) = lo;
    }
    if (t < 64) *(float*)(lds + 32768 + t * 4) = sreg;

    __syncthreads();

    // issue next-iter loads NOW: drained one full compute phase from here
    if (it + 1 < iters) {
      const float* abase = Xtr + (size_t)(M0 + (it + 1) * 64) * 128;
#pragma unroll
      for (int j = 0; j < 4; ++j) {
        int c = t + j * 256;
        int row = c >> 4, oct = c & 15;
        const float* p = abase + (size_t)row * 128 + oct * 8;
        ga[j][0] = *(const float4*)p;
        ga[j][1] = *(const float4*)(p + 4);
      }
      if (t < 64) sreg = s[M0 + (it + 1) * 64 + t];
    }

#pragma unroll
    for (int mf = 0; mf < 2; ++mf) {
      f32x16 acc0 = {0, 0, 0, 0, 0, 0, 0, 0, 0, 0, 0, 0, 0, 0, 0, 0};
      f32x16 acc1 = {0, 0, 0, 0, 0, 0, 0, 0, 0, 0, 0, 0, 0, 0, 0, 0};
      __builtin_amdgcn_s_setprio(1);
#pragma unroll
      for (int kf = 0; kf < 8; ++kf) {
        unsigned off =
            swz((unsigned)((mf * 32 + lrow) * 256 + kf * 32 + lk * 16));
        short8 ah = *(const short8*)(lds + off);
        short8 al = *(const short8*)(lds + 16384 + off);
        acc0 = __builtin_amdgcn_mfma_f32_32x32x16_bf16(ah, bh[0][kf], acc0, 0, 0, 0);
        acc1 = __builtin_amdgcn_mfma_f32_32x32x16_bf16(ah, bh[1][kf], acc1, 0, 0, 0);
        acc0 = __builtin_amdgcn_mfma_f32_32x32x16_bf16(ah, bl[0][kf], acc0, 0, 0, 0);
        acc1 = __builtin_amdgcn_mfma_f32_32x32x16_bf16(ah, bl[1][kf], acc1, 0, 0, 0);
        acc0 = __builtin_amdgcn_mfma_f32_32x32x16_bf16(al, bh[0][kf], acc0, 0, 0, 0);
        acc1 = __builtin_amdgcn_mfma_f32_32x32x16_bf16(al, bh[1][kf], acc1, 0, 0, 0);
      }
      __builtin_amdgcn_s_setprio(0);
      const float* sl = (const float*)(lds + 32768 + mf * 128);
#pragma unroll
      for (int r = 0; r < 16; ++r) {
        int row = (r & 3) + 8 * (r >> 2) + 4 * lk;
        float sv = sl[row];
        out0 += fast_exp2(acc0[r]) * sv;
        out1 += fast_exp2(acc1[r]) * sv;
      }
    }
  }

  out0 += __shfl_xor(out0, 32, 64);
  out1 += __shfl_xor(out1, 32, 64);
  if (l < 32) {
    int n = n0 + w * 64 + l;
    atomicAdd(out + n, pref[n] * out0);
    n += 32;
    atomicAdd(out + n, pref[n] * out1);
  }
}

extern "C" void kernel_launch(void* const* d_in, const int* in_sizes, int n_in,
                              void* d_out, int out_size, void* d_ws,
                              size_t ws_size, hipStream_t stream) {
  const float* Xnew = (const float*)d_in[0];
  const float* Xtr = (const float*)d_in[1];
  const float* wts = (const float*)d_in[2];
  float* out = (float*)d_out;

  const int N = in_sizes[0] / 128;  // 8192
  const int M = in_sizes[1] / 128;  // 32768

  char* ws = (char*)d_ws;
  float* s_ws = (float*)ws;                       // [M]
  float* pref_ws = s_ws + M;                      // [N]
  char* hi_ws = ws + (size_t)(M + N) * 4;         // [M*256 B], 16B-aligned
  char* lo_ws = hi_ws + (size_t)M * 256;          // [M*256 B]
  const size_t need = (size_t)(M + N) * 4 + (size_t)M * 512;

  hipMemsetAsync(d_out, 0, (size_t)N * sizeof(float), stream);

  int rows = M + N;
  gk_prep<<<dim3((rows + 3) / 4), 256, 0, stream>>>(Xnew, Xtr, wts, s_ws,
                                                    pref_ws, M, N);

  const int SPLIT = 16;
  dim3 grid(N / 256, SPLIT);
  if (ws_size >= need) {
    gk_conv<<<dim3(M * 16 / 256), 256, 0, stream>>>(Xtr, hi_ws, lo_ws, M);
    gk_main_fast<<<grid, 256, 66048, stream>>>(Xnew, hi_ws, lo_ws, s_ws,
                                               pref_ws, out, N, M, M / SPLIT);
  } else {
    gk_main_fb<<<grid, 256, 0, stream>>>(Xnew, Xtr, s_ws, pref_ws, out, N, M,
                                         M / SPLIT);
  }
}